// Round 22
// baseline (84.206 us; speedup 1.0000x reference)
//
#include <hip/hip_runtime.h>

// 8-level sym8 wavelet packet transform, B=128 rows of L0=65536, f32.
// dwt_f03_eo<EDGE>: levels 0-3, segmented virtual-tile chain, POLYPHASE E/O
// LDS tiles, interleaved float4 store. EDGE=false (segs 1..14): all guards
// and edge-reflect paths deleted at compile time -> branch-free stages with
// the quad's register-clean code shape. EDGE=true (segs 0,15): guarded.
// dwt_quad_eo: levels 4-7 (R18 verbatim): linear global_load_lds DMA,
// LDS->LDS deinterleave, 28-slot margin fixup, polyphase, fused log.

#define BT 512

__device__ __constant__ float FL[16] = {
     0.0018899503327594609f, -0.0003029205147213668f, -0.01495225833704823f,
     0.003808752013890615f,   0.049137179673607506f,  -0.027219029917056003f,
    -0.05194583810770904f,    0.3644418948353314f,     0.7771857517005235f,
     0.4813596512583722f,    -0.061273359067658524f,  -0.1432942383508097f,
     0.007607487324917605f,   0.03169508781149298f,   -0.0005421323317911481f,
    -0.0033824159510061256f
};
__device__ __constant__ float FH[16] = {
     0.0033824159510061256f, -0.0005421323317911481f, -0.03169508781149298f,
     0.007607487324917605f,   0.1432942383508097f,    -0.061273359067658524f,
    -0.4813596512583722f,     0.7771857517005235f,    -0.3644418948353314f,
    -0.05194583810770904f,    0.027219029917056003f,   0.049137179673607506f,
    -0.003808752013890615f,  -0.01495225833704823f,    0.0003029205147213668f,
     0.0018899503327594609f
};
// Even/odd split: FLE[k]=FL[2k], FLO[k]=FL[2k+1], same for FH.
__device__ __constant__ float FLE[8] = {
     0.0018899503327594609f, -0.01495225833704823f,  0.049137179673607506f,
    -0.05194583810770904f,   0.7771857517005235f,   -0.061273359067658524f,
     0.007607487324917605f, -0.0005421323317911481f };
__device__ __constant__ float FLO[8] = {
    -0.0003029205147213668f, 0.003808752013890615f, -0.027219029917056003f,
     0.3644418948353314f,    0.4813596512583722f,   -0.1432942383508097f,
     0.03169508781149298f,  -0.0033824159510061256f };
__device__ __constant__ float FHE[8] = {
     0.0033824159510061256f, -0.03169508781149298f,  0.1432942383508097f,
    -0.4813596512583722f,   -0.3644418948353314f,    0.027219029917056003f,
    -0.003808752013890615f,  0.0003029205147213668f };
__device__ __constant__ float FHO[8] = {
    -0.0005421323317911481f, 0.007607487324917605f, -0.061273359067658524f,
     0.7771857517005235f,   -0.05194583810770904f,   0.049137179673607506f,
    -0.01495225833704823f,   0.0018899503327594609f };

__device__ __forceinline__ int reflect(int q, int L) {
    q = (q < 0) ? -q : q;
    return (q >= L) ? (2 * L - 2 - q) : q;
}

__device__ __forceinline__ void gload_lds16(const float* g, float* l) {
    __builtin_amdgcn_global_load_lds(
        (const __attribute__((address_space(1))) void*)g,
        (__attribute__((address_space(3))) void*)l, 16, 0, 0);
}

__device__ __forceinline__ void read12(const float* __restrict__ b, int w0,
                                       float* __restrict__ r) {
#pragma unroll
    for (int k = 0; k < 3; ++k) {
        const float4 v = *reinterpret_cast<const float4*>(&b[w0 + 4 * k]);
        r[4 * k] = v.x; r[4 * k + 1] = v.y; r[4 * k + 2] = v.z; r[4 * k + 3] = v.w;
    }
}

// 4 outputs (both filters) from E/O windows; tap for output d: e/o[OFF+d+s].
template <int OFF>
__device__ __forceinline__ void conv4eo(const float e[12], const float o[12],
                                        float lo[4], float hi[4]) {
#pragma unroll
    for (int d = 0; d < 4; ++d) { lo[d] = 0.f; hi[d] = 0.f; }
#pragma unroll
    for (int s = 0; s < 8; ++s) {
        const float fle = FLE[s], flo = FLO[s], fhe = FHE[s], fho = FHO[s];
#pragma unroll
        for (int d = 0; d < 4; ++d) {
            const float ev = e[OFF + d + s], ov = o[OFF + d + s];
            lo[d] = fmaf(ev, fle, lo[d]);
            lo[d] = fmaf(ov, flo, lo[d]);
            hi[d] = fmaf(ev, fhe, hi[d]);
            hi[d] = fmaf(ov, fho, hi[d]);
        }
    }
}

// Scalar polyphase conv at rel window start s.
__device__ __forceinline__ void conv1s(const float* __restrict__ E,
                                       const float* __restrict__ O,
                                       int s, float& lo, float& hi) {
    lo = hi = 0.f;
#pragma unroll
    for (int k = 0; k < 8; ++k) {
        const float ev = E[s + k], ov = O[s + k];
        lo = fmaf(ev, FLE[k], lo);
        lo = fmaf(ov, FLO[k], lo);
        hi = fmaf(ev, FHE[k], hi);
        hi = fmaf(ov, FHO[k], hi);
    }
}

// E/O ext arrays (quad): virtual position q -> slot 8+(q>>1) in E/O.
__device__ __forceinline__ void eo_put(float* __restrict__ E, float* __restrict__ O,
                                       int q, float v) {
    ((q & 1) ? O : E)[8 + (q >> 1)] = v;
}

// ======================= F03: levels 0-3, polyphase, templated =======================
template <bool EDGE, int Pin, int NV, int SEp, int SEc, int Lc>
__device__ __forceinline__ void f03_stage_eo(const float* __restrict__ inb,
                                             float* __restrict__ outb, int o_lo) {
    for (int g = threadIdx.x; g < Pin * NV; g += BT) {
        const int r = g / NV;                   // compile-time divisor
        const int v = g - r * NV;
        const float* PE = inb + r * (2 * SEp);
        const float* PO = PE + SEp;
        float lo[4], hi[4];
        if (!EDGE) {                            // interior: branch-free blind path
            float e[12], o[12];
            read12(PE, 4 * v, e);
            read12(PO, 4 * v, o);
            conv4eo<0>(e, o, lo, hi);
        } else {
            const int s0 = 4 * v;
            const int q0 = o_lo + s0;
            if (q0 >= 0 && q0 + 4 <= Lc) {
                float e[12], o[12];
                read12(PE, 4 * v, e);
                read12(PO, 4 * v, o);
                conv4eo<0>(e, o, lo, hi);
            } else {
#pragma unroll
                for (int d = 0; d < 4; ++d) {
                    const int jr = reflect(q0 + d, Lc);
                    conv1s(PE, PO, jr - o_lo, lo[d], hi[d]);
                }
            }
        }
        float* CEl = outb + (2 * r) * (2 * SEc);
        float* COl = CEl + SEc;
        float* CEh = outb + (2 * r + 1) * (2 * SEc);
        float* COh = CEh + SEc;
        *reinterpret_cast<float2*>(&CEl[2 * v]) = make_float2(lo[0], lo[2]);
        *reinterpret_cast<float2*>(&COl[2 * v]) = make_float2(lo[1], lo[3]);
        *reinterpret_cast<float2*>(&CEh[2 * v]) = make_float2(hi[0], hi[2]);
        *reinterpret_cast<float2*>(&COh[2 * v]) = make_float2(hi[1], hi[3]);
    }
}

template <bool EDGE>
__global__ __launch_bounds__(BT, 8) void dwt_f03_eo(
    const float* __restrict__ x, float* __restrict__ y) {
    // tile E-strides (all mult 4): x 2200, lev0 1096, lev1 544, lev2 268
    __shared__ __align__(16) float bufA[4400];  // x [E|O] | lev1 4x[E|O] (4352)
    __shared__ __align__(16) float bufB[4384];  // lev0 2x[E|O] | lev2 8x[E|O] (4288)

    constexpr int M = 260;                      // lev3 outputs per segment
    const int seg = EDGE ? (blockIdx.x * 15) : (blockIdx.x + 1);
    const int n   = blockIdx.y;
    const int b0  = M * seg;                    // mult of 4
    const int a2  = 2 * b0 - 14;
    const int c1  = 4 * b0 - 42;
    const int a0  = 8 * b0 - 98;
    const int px0 = 16 * b0 - 210;              // even
    const float* row = x + (size_t)n * 65536;

    // ---- x-tile fill: deinterleave into XE/XO (rel parity) ----
    float* XE = bufA;
    float* XO = bufA + 2200;
    if (!EDGE) {                                // interior: always in-bounds
        const float2* rp = reinterpret_cast<const float2*>(row + px0);
        for (int i = threadIdx.x; i < 2200; i += BT) {
            const float2 v = rp[i];
            XE[i] = v.x; XO[i] = v.y;
        }
    } else {
        for (int i = threadIdx.x; i < 2200; i += BT) {
            XE[i] = row[reflect(px0 + 2 * i, 65536)];
            XO[i] = row[reflect(px0 + 2 * i + 1, 65536)];
        }
    }
    __syncthreads();

    f03_stage_eo<EDGE, 1, 548, 2200, 1096, 32775>(bufA, bufB, a0);  // x -> lev0
    __syncthreads();
    f03_stage_eo<EDGE, 2, 272, 1096, 544, 16395>(bufB, bufA, c1);   // -> lev1
    __syncthreads();
    f03_stage_eo<EDGE, 4, 134, 544, 268, 8205>(bufA, bufB, a2);     // -> lev2
    __syncthreads();

    // ---- final: lev2 -> lev3 genuine, interleaved float4 global ----
    {
        constexpr int NVF = 65;                 // M/4
        float* yg = y + (size_t)(16 * n) * 4112;
        for (int g = threadIdx.x; g < 8 * NVF; g += BT) {
            const int r  = g / NVF;
            const int v  = g - r * NVF;
            const int j0 = b0 + 4 * v;          // mult of 4
            if (EDGE && j0 >= 4110) continue;
            const float* PE = bufB + r * (2 * 268);
            const float* PO = PE + 268;
            float e[12], o[12];
            read12(PE, 4 * v, e);
            read12(PO, 4 * v, o);
            float lo[4], hi[4];
            conv4eo<0>(e, o, lo, hi);
            float* y0 = yg + (size_t)(2 * r) * 4112 + j0;
            float* y1 = y0 + 4112;
            if (!EDGE || j0 + 4 <= 4110) {
                *reinterpret_cast<float4*>(y0) = make_float4(lo[0], lo[1], lo[2], lo[3]);
                *reinterpret_cast<float4*>(y1) = make_float4(hi[0], hi[1], hi[2], hi[3]);
            } else {                            // j0 = 4108: 2 valid outputs
                *reinterpret_cast<float2*>(y0) = make_float2(lo[0], lo[1]);
                *reinterpret_cast<float2*>(y1) = make_float2(hi[0], hi[1]);
            }
        }
    }
}

// ================= Polyphase quad kernel (levels 4-7, R18 verbatim) =================
template <int Ls, int P, int Sin, int Sout, bool LOG>
__device__ __forceinline__ void stage_eo(const float* __restrict__ inb,
                                         float* __restrict__ outb,
                                         float* __restrict__ outg) {
    constexpr int H    = Ls / 2;
    constexpr int LOUT = H + 7;
    constexpr int GPS  = (LOUT + 3) / 4;
    constexpr int SEi  = Sin / 2;
    constexpr int SEo  = Sout / 2;
    for (int g = threadIdx.x; g < P * GPS; g += BT) {
        const int p  = g / GPS;
        const int u  = g - p * GPS;
        const int j0 = 4 * u;
        const float* Ei = inb + p * Sin;
        const float* Oi = Ei + SEi;
        float e[12], o[12];
        read12(Ei, 4 * u, e);
        read12(Oi, 4 * u, o);
        float lo[4], hi[4];
        conv4eo<1>(e, o, lo, hi);
        if (LOG) {
            float r0[4], r1[4];
#pragma unroll
            for (int d = 0; d < 4; ++d) {
                r0[d] = __logf(fmaf(lo[d], lo[d], 1e-12f));
                r1[d] = __logf(fmaf(hi[d], hi[d], 1e-12f));
            }
            float* y0 = outg + (2 * p) * 270 + j0;
            float* y1 = y0 + 270;
            if (j0 + 3 < 270) {
                *reinterpret_cast<float2*>(y0)     = make_float2(r0[0], r0[1]);
                *reinterpret_cast<float2*>(y0 + 2) = make_float2(r0[2], r0[3]);
                *reinterpret_cast<float2*>(y1)     = make_float2(r1[0], r1[1]);
                *reinterpret_cast<float2*>(y1 + 2) = make_float2(r1[2], r1[3]);
            } else {
                *reinterpret_cast<float2*>(y0) = make_float2(r0[0], r0[1]);
                *reinterpret_cast<float2*>(y1) = make_float2(r1[0], r1[1]);
            }
        } else {
            float* El = outb + (2 * p) * Sout;
            float* Ol = El + SEo;
            float* Eh = outb + (2 * p + 1) * Sout;
            float* Oh = Eh + SEo;
            if (j0 + 3 < LOUT) {
                *reinterpret_cast<float2*>(&El[8 + 2 * u]) = make_float2(lo[0], lo[2]);
                *reinterpret_cast<float2*>(&Ol[8 + 2 * u]) = make_float2(lo[1], lo[3]);
                *reinterpret_cast<float2*>(&Eh[8 + 2 * u]) = make_float2(hi[0], hi[2]);
                *reinterpret_cast<float2*>(&Oh[8 + 2 * u]) = make_float2(hi[1], hi[3]);
            } else {
#pragma unroll
                for (int d = 0; d < 4; ++d)
                    if (j0 + d < LOUT) {
                        eo_put(El, Ol, j0 + d, lo[d]);
                        eo_put(Eh, Oh, j0 + d, hi[d]);
                    }
            }
            if (j0 <= 14 || j0 >= LOUT - 18) {
#pragma unroll
                for (int d = 0; d < 4; ++d) {
                    const int j = j0 + d;
                    if (j >= 1 && j <= 14) {
                        eo_put(El, Ol, -j, lo[d]);
                        eo_put(Eh, Oh, -j, hi[d]);
                    }
                    if (j >= LOUT - 15 && j <= LOUT - 2) {
                        eo_put(El, Ol, 2 * LOUT - 2 - j, lo[d]);
                        eo_put(Eh, Oh, 2 * LOUT - 2 - j, hi[d]);
                    }
                }
            }
        }
    }
}

__global__ __launch_bounds__(BT, 8) void dwt_quad_eo(
    const float* __restrict__ x, float* __restrict__ y) {
    __shared__ __align__(16) float bufA[4320];  // E/O ext 4152 | s2-out 4x1080
    __shared__ __align__(16) float bufB[4544];  // staging 4352 / s1 2x2104 | s3 8x568

    const int m = blockIdx.x;
    const float* row = x + (size_t)m * 4112;    // interleaved lev3 row

    // 1) linear DMA into staging: 17 chunks x 1024B = 4352 floats (tail junk)
    const int wave = threadIdx.x >> 6;
    const int lane = threadIdx.x & 63;
    for (int c = wave; c < 17; c += 8)
        gload_lds16(row + c * 256 + lane * 4, &bufB[c * 256]);
    __syncthreads();

    // 2) LDS->LDS deinterleave into E/O ext
    float* Ex = bufA;
    float* Ox = bufA + 2076;
    for (int q = threadIdx.x; q < 1028; q += BT) {
        const float4 v = *reinterpret_cast<const float4*>(&bufB[4 * q]);
        *reinterpret_cast<float2*>(&Ex[8 + 2 * q]) = make_float2(v.x, v.z);
        *reinterpret_cast<float2*>(&Ox[8 + 2 * q]) = make_float2(v.y, v.w);
    }
    __syncthreads();

    // 3) rebuild the 28 reflect-margin slots (junk at slot 2063 overwritten)
    if (threadIdx.x < 28) {
        const int t = threadIdx.x;
        if (t < 7)       Ex[7 - t]           = Ex[9 + t];
        else if (t < 14) Ox[14 - t]          = Ox[t + 1];
        else if (t < 21) Ex[2063 + (t - 14)] = Ex[2062 - (t - 14)];
        else             Ox[2063 + (t - 21)] = Ox[2061 - (t - 21)];
    }
    __syncthreads();

    stage_eo<4110, 1, 4152, 2104, false>(bufA, bufB, nullptr);  // -> 2x2062
    __syncthreads();
    stage_eo<2062, 2, 2104, 1080, false>(bufB, bufA, nullptr);  // -> 4x1038
    __syncthreads();
    stage_eo<1038, 4, 1080, 568, false>(bufA, bufB, nullptr);   // -> 8x526
    __syncthreads();
    stage_eo<526, 8, 568, 0, true>(bufB, nullptr, y + (size_t)m * 4320); // 16x270
}

extern "C" void kernel_launch(void* const* d_in, const int* in_sizes, int n_in,
                              void* d_out, int out_size, void* d_ws, size_t ws_size,
                              hipStream_t stream) {
    const float* in = (const float*)d_in[0];
    float* out = (float*)d_out;
    float* wsB = (float*)d_ws;              // lev3: 2048 rows, stride 4112 (+DMA slack)
    (void)ws_size; (void)out_size; (void)n_in; (void)in_sizes;

    // F03 interior: segs 1..14 (branch-free polyphase)
    { dim3 g(14, 128); dwt_f03_eo<false><<<g, BT, 0, stream>>>(in, wsB); }
    // F03 edge: segs 0, 15 (guarded)
    { dim3 g(2, 128);  dwt_f03_eo<true><<<g, BT, 0, stream>>>(in, wsB); }
    // F47: levels 4-7 (+log); DMA ingest + in-LDS deinterleave
    dwt_quad_eo<<<2048, BT, 0, stream>>>(wsB, out);
}

// Round 23
// 70.702 us; speedup vs baseline: 1.1910x; 1.1910x over previous
//
#include <hip/hip_runtime.h>

// 8-level sym8 wavelet packet transform, B=128 rows of L0=65536, f32.
// FINAL (R18/R20 configuration, measured 70.7-70.9 us):
// dwt_f03: levels 0-3, segmented virtual-tile LDS chain (interleaved tiles,
// load20/conv2 structure — the register-allocator-friendly form), writes
// lev3 interleaved (stride 4112).
// dwt_quad_eo: levels 4-7: linear global_load_lds DMA of the interleaved
// row into LDS staging, LDS->LDS deinterleave into E/O ext, 28-slot
// reflect-margin fixup, then polyphase stages; final level fuses
// log(x^2 + 1e-12).

#define BT 512

__device__ __constant__ float FL[16] = {
     0.0018899503327594609f, -0.0003029205147213668f, -0.01495225833704823f,
     0.003808752013890615f,   0.049137179673607506f,  -0.027219029917056003f,
    -0.05194583810770904f,    0.3644418948353314f,     0.7771857517005235f,
     0.4813596512583722f,    -0.061273359067658524f,  -0.1432942383508097f,
     0.007607487324917605f,   0.03169508781149298f,   -0.0005421323317911481f,
    -0.0033824159510061256f
};
__device__ __constant__ float FH[16] = {
     0.0033824159510061256f, -0.0005421323317911481f, -0.03169508781149298f,
     0.007607487324917605f,   0.1432942383508097f,    -0.061273359067658524f,
    -0.4813596512583722f,     0.7771857517005235f,    -0.3644418948353314f,
    -0.05194583810770904f,    0.027219029917056003f,   0.049137179673607506f,
    -0.003808752013890615f,  -0.01495225833704823f,    0.0003029205147213668f,
     0.0018899503327594609f
};
// Even/odd split (polyphase quad)
__device__ __constant__ float FLE[8] = {
     0.0018899503327594609f, -0.01495225833704823f,  0.049137179673607506f,
    -0.05194583810770904f,   0.7771857517005235f,   -0.061273359067658524f,
     0.007607487324917605f, -0.0005421323317911481f };
__device__ __constant__ float FLO[8] = {
    -0.0003029205147213668f, 0.003808752013890615f, -0.027219029917056003f,
     0.3644418948353314f,    0.4813596512583722f,   -0.1432942383508097f,
     0.03169508781149298f,  -0.0033824159510061256f };
__device__ __constant__ float FHE[8] = {
     0.0033824159510061256f, -0.03169508781149298f,  0.1432942383508097f,
    -0.4813596512583722f,   -0.3644418948353314f,    0.027219029917056003f,
    -0.003808752013890615f,  0.0003029205147213668f };
__device__ __constant__ float FHO[8] = {
    -0.0005421323317911481f, 0.007607487324917605f, -0.061273359067658524f,
     0.7771857517005235f,   -0.05194583810770904f,   0.049137179673607506f,
    -0.01495225833704823f,   0.0018899503327594609f };

__device__ __forceinline__ int reflect(int q, int L) {
    q = (q < 0) ? -q : q;
    return (q >= L) ? (2 * L - 2 - q) : q;
}

__device__ __forceinline__ void gload_lds16(const float* g, float* l) {
    __builtin_amdgcn_global_load_lds(
        (const __attribute__((address_space(1))) void*)g,
        (__attribute__((address_space(3))) void*)l, 16, 0, 0);
}

__device__ __forceinline__ void load20(const float* __restrict__ lds, int base,
                                       float w[20]) {
#pragma unroll
    for (int k = 0; k < 5; ++k) {
        const float4 v = *reinterpret_cast<const float4*>(&lds[base + 4 * k]);
        w[4 * k] = v.x; w[4 * k + 1] = v.y; w[4 * k + 2] = v.z; w[4 * k + 3] = v.w;
    }
}

__device__ __forceinline__ void conv2(const float w[20], float& lo0, float& hi0,
                                      float& lo1, float& hi1) {
    lo0 = hi0 = lo1 = hi1 = 0.f;
#pragma unroll
    for (int t = 0; t < 16; ++t) {
        const float cl = FL[t], ch = FH[t];
        lo0 = fmaf(w[t], cl, lo0);
        hi0 = fmaf(w[t], ch, hi0);
        lo1 = fmaf(w[t + 2], cl, lo1);
        hi1 = fmaf(w[t + 2], ch, hi1);
    }
}

// E/O ext arrays: virtual position q -> slot 8 + (q>>1) in E (even) / O (odd).
__device__ __forceinline__ void eo_put(float* __restrict__ E, float* __restrict__ O,
                                       int q, float v) {
    ((q & 1) ? O : E)[8 + (q >> 1)] = v;
}

// ======================= F03: levels 0-3 (R14 structure) =======================
template <int Pin, int Wout, int Sin, int Sout, int Lc>
__device__ __forceinline__ void f03_stage(const float* __restrict__ in,
                                          float* __restrict__ out, int o_lo) {
    constexpr int GPS = Wout / 2;
    for (int g = threadIdx.x; g < Pin * GPS; g += BT) {
        const int r = g / GPS;                  // compile-time divisor
        const int u = g - r * GPS;
        const int s0 = 2 * u;
        const int q0 = o_lo + s0;
        const float* pin = in + r * Sin;
        float lo0, hi0, lo1, hi1;
        if (q0 >= 0 && q0 + 2 <= Lc) {
            float w[20];
            load20(pin, 4 * u, w);
            conv2(w, lo0, hi0, lo1, hi1);
        } else {                                // segs 0/15 only
#pragma unroll
            for (int e = 0; e < 2; ++e) {
                const int jr = reflect(q0 + e, Lc);
                const int rb = 2 * (jr - o_lo);
                float l = 0.f, h = 0.f;
#pragma unroll
                for (int t = 0; t < 16; ++t) {
                    const float v = pin[rb + t];
                    l = fmaf(v, FL[t], l);
                    h = fmaf(v, FH[t], h);
                }
                if (e == 0) { lo0 = l; hi0 = h; } else { lo1 = l; hi1 = h; }
            }
        }
        *reinterpret_cast<float2*>(&out[(2 * r) * Sout + s0])     = make_float2(lo0, lo1);
        *reinterpret_cast<float2*>(&out[(2 * r + 1) * Sout + s0]) = make_float2(hi0, hi1);
    }
}

__global__ __launch_bounds__(BT, 8) void dwt_f03(
    const float* __restrict__ x, float* __restrict__ y) {
    constexpr int M  = 258;
    constexpr int WX = 4338, SX = 4340;
    constexpr int W0 = 2162, S0 = 2164;
    constexpr int W1 = 1074, S1 = 1076;
    constexpr int W2 = 530,  S2 = 532;
    __shared__ __align__(16) float bufA[4340];  // x ext | lev1 (4*1076)
    __shared__ __align__(16) float bufB[4328];  // lev0 (2*2164) | lev2 (8*532)

    const int seg = blockIdx.x;
    const int n   = blockIdx.y;
    const int b0  = M * seg;
    const int a2  = 2 * b0 - 14;
    const int c1  = 4 * b0 - 42;
    const int a0  = 8 * b0 - 98;
    const int px0 = 16 * b0 - 210;
    const float* row = x + (size_t)n * 65536;

    if (px0 >= 0 && px0 + WX <= 65536) {
        const float2* rp = reinterpret_cast<const float2*>(row + px0);
        for (int h = threadIdx.x; h < WX / 2; h += BT)
            *reinterpret_cast<float2*>(&bufA[2 * h]) = rp[h];
    } else {
        for (int p = threadIdx.x; p < WX; p += BT)
            bufA[p] = row[reflect(px0 + p, 65536)];
    }
    __syncthreads();

    f03_stage<1, W0, SX, S0, 32775>(bufA, bufB, a0);   // x    -> lev0 (2)
    __syncthreads();
    f03_stage<2, W1, S0, S1, 16395>(bufB, bufA, c1);   // lev0 -> lev1 (4)
    __syncthreads();
    f03_stage<4, W2, S1, S2, 8205>(bufA, bufB, a2);    // lev1 -> lev2 (8)
    __syncthreads();

    // final: lev2 -> lev3 genuine, interleaved global (stride 4112)
    {
        constexpr int GPS = M / 2;              // 129
        float* yg = y + (size_t)(16 * n) * 4112;
        for (int g = threadIdx.x; g < 8 * GPS; g += BT) {
            const int r  = g / GPS;
            const int u  = g - r * GPS;
            const int j0 = b0 + 2 * u;
            if (j0 >= 4110) continue;
            float w[20];
            load20(bufB + r * S2, 4 * u, w);
            float lo0, hi0, lo1, hi1;
            conv2(w, lo0, hi0, lo1, hi1);
            float* y0 = yg + (size_t)(2 * r) * 4112 + j0;
            float* y1 = y0 + 4112;
            if (j0 + 1 < 4110) {
                *reinterpret_cast<float2*>(y0) = make_float2(lo0, lo1);
                *reinterpret_cast<float2*>(y1) = make_float2(hi0, hi1);
            } else {
                y0[0] = lo0; y1[0] = hi0;
            }
        }
    }
}

// ================= Polyphase quad kernel (levels 4-7) =================
__device__ __forceinline__ void read12(const float* __restrict__ b, int w0,
                                       float* __restrict__ r) {
#pragma unroll
    for (int k = 0; k < 3; ++k) {
        const float4 v = *reinterpret_cast<const float4*>(&b[w0 + 4 * k]);
        r[4 * k] = v.x; r[4 * k + 1] = v.y; r[4 * k + 2] = v.z; r[4 * k + 3] = v.w;
    }
}

template <int OFF>
__device__ __forceinline__ void conv4eo(const float e[12], const float o[12],
                                        float lo[4], float hi[4]) {
#pragma unroll
    for (int d = 0; d < 4; ++d) { lo[d] = 0.f; hi[d] = 0.f; }
#pragma unroll
    for (int s = 0; s < 8; ++s) {
        const float fle = FLE[s], flo = FLO[s], fhe = FHE[s], fho = FHO[s];
#pragma unroll
        for (int d = 0; d < 4; ++d) {
            const float ev = e[OFF + d + s], ov = o[OFF + d + s];
            lo[d] = fmaf(ev, fle, lo[d]);
            lo[d] = fmaf(ov, flo, lo[d]);
            hi[d] = fmaf(ev, fhe, hi[d]);
            hi[d] = fmaf(ov, fho, hi[d]);
        }
    }
}

template <int Ls, int P, int Sin, int Sout, bool LOG>
__device__ __forceinline__ void stage_eo(const float* __restrict__ inb,
                                         float* __restrict__ outb,
                                         float* __restrict__ outg) {
    constexpr int H    = Ls / 2;
    constexpr int LOUT = H + 7;
    constexpr int GPS  = (LOUT + 3) / 4;
    constexpr int SEi  = Sin / 2;
    constexpr int SEo  = Sout / 2;
    for (int g = threadIdx.x; g < P * GPS; g += BT) {
        const int p  = g / GPS;
        const int u  = g - p * GPS;
        const int j0 = 4 * u;
        const float* Ei = inb + p * Sin;
        const float* Oi = Ei + SEi;
        float e[12], o[12];
        read12(Ei, 4 * u, e);
        read12(Oi, 4 * u, o);
        float lo[4], hi[4];
        conv4eo<1>(e, o, lo, hi);
        if (LOG) {
            float r0[4], r1[4];
#pragma unroll
            for (int d = 0; d < 4; ++d) {
                r0[d] = __logf(fmaf(lo[d], lo[d], 1e-12f));
                r1[d] = __logf(fmaf(hi[d], hi[d], 1e-12f));
            }
            float* y0 = outg + (2 * p) * 270 + j0;
            float* y1 = y0 + 270;
            if (j0 + 3 < 270) {
                *reinterpret_cast<float2*>(y0)     = make_float2(r0[0], r0[1]);
                *reinterpret_cast<float2*>(y0 + 2) = make_float2(r0[2], r0[3]);
                *reinterpret_cast<float2*>(y1)     = make_float2(r1[0], r1[1]);
                *reinterpret_cast<float2*>(y1 + 2) = make_float2(r1[2], r1[3]);
            } else {
                *reinterpret_cast<float2*>(y0) = make_float2(r0[0], r0[1]);
                *reinterpret_cast<float2*>(y1) = make_float2(r1[0], r1[1]);
            }
        } else {
            float* El = outb + (2 * p) * Sout;
            float* Ol = El + SEo;
            float* Eh = outb + (2 * p + 1) * Sout;
            float* Oh = Eh + SEo;
            if (j0 + 3 < LOUT) {
                *reinterpret_cast<float2*>(&El[8 + 2 * u]) = make_float2(lo[0], lo[2]);
                *reinterpret_cast<float2*>(&Ol[8 + 2 * u]) = make_float2(lo[1], lo[3]);
                *reinterpret_cast<float2*>(&Eh[8 + 2 * u]) = make_float2(hi[0], hi[2]);
                *reinterpret_cast<float2*>(&Oh[8 + 2 * u]) = make_float2(hi[1], hi[3]);
            } else {
#pragma unroll
                for (int d = 0; d < 4; ++d)
                    if (j0 + d < LOUT) {
                        eo_put(El, Ol, j0 + d, lo[d]);
                        eo_put(Eh, Oh, j0 + d, hi[d]);
                    }
            }
            if (j0 <= 14 || j0 >= LOUT - 18) {
#pragma unroll
                for (int d = 0; d < 4; ++d) {
                    const int j = j0 + d;
                    if (j >= 1 && j <= 14) {
                        eo_put(El, Ol, -j, lo[d]);
                        eo_put(Eh, Oh, -j, hi[d]);
                    }
                    if (j >= LOUT - 15 && j <= LOUT - 2) {
                        eo_put(El, Ol, 2 * LOUT - 2 - j, lo[d]);
                        eo_put(Eh, Oh, 2 * LOUT - 2 - j, hi[d]);
                    }
                }
            }
        }
    }
}

__global__ __launch_bounds__(BT, 8) void dwt_quad_eo(
    const float* __restrict__ x, float* __restrict__ y) {
    __shared__ __align__(16) float bufA[4320];  // E/O ext 4152 | s2-out 4x1080
    __shared__ __align__(16) float bufB[4544];  // staging 4352 / s1 2x2104 | s3 8x568

    const int m = blockIdx.x;
    const float* row = x + (size_t)m * 4112;    // interleaved lev3 row

    // 1) linear DMA into staging: 17 chunks x 1024B = 4352 floats (tail junk)
    const int wave = threadIdx.x >> 6;
    const int lane = threadIdx.x & 63;
    for (int c = wave; c < 17; c += 8)
        gload_lds16(row + c * 256 + lane * 4, &bufB[c * 256]);
    __syncthreads();

    // 2) LDS->LDS deinterleave into E/O ext
    float* Ex = bufA;
    float* Ox = bufA + 2076;
    for (int q = threadIdx.x; q < 1028; q += BT) {
        const float4 v = *reinterpret_cast<const float4*>(&bufB[4 * q]);
        *reinterpret_cast<float2*>(&Ex[8 + 2 * q]) = make_float2(v.x, v.z);
        *reinterpret_cast<float2*>(&Ox[8 + 2 * q]) = make_float2(v.y, v.w);
    }
    __syncthreads();

    // 3) rebuild the 28 reflect-margin slots (junk at slot 2063 overwritten)
    if (threadIdx.x < 28) {
        const int t = threadIdx.x;
        if (t < 7)       Ex[7 - t]           = Ex[9 + t];
        else if (t < 14) Ox[14 - t]          = Ox[t + 1];
        else if (t < 21) Ex[2063 + (t - 14)] = Ex[2062 - (t - 14)];
        else             Ox[2063 + (t - 21)] = Ox[2061 - (t - 21)];
    }
    __syncthreads();

    stage_eo<4110, 1, 4152, 2104, false>(bufA, bufB, nullptr);  // -> 2x2062
    __syncthreads();
    stage_eo<2062, 2, 2104, 1080, false>(bufB, bufA, nullptr);  // -> 4x1038
    __syncthreads();
    stage_eo<1038, 4, 1080, 568, false>(bufA, bufB, nullptr);   // -> 8x526
    __syncthreads();
    stage_eo<526, 8, 568, 0, true>(bufB, nullptr, y + (size_t)m * 4320); // 16x270
}

extern "C" void kernel_launch(void* const* d_in, const int* in_sizes, int n_in,
                              void* d_out, int out_size, void* d_ws, size_t ws_size,
                              hipStream_t stream) {
    const float* in = (const float*)d_in[0];
    float* out = (float*)d_out;
    float* wsB = (float*)d_ws;              // lev3: 2048 rows, stride 4112 (+DMA slack)
    (void)ws_size; (void)out_size; (void)n_in; (void)in_sizes;

    // F03: levels 0-3; 16 segs x 128 rows
    { dim3 g(16, 128); dwt_f03<<<g, BT, 0, stream>>>(in, wsB); }
    // F47: levels 4-7 (+log); DMA ingest + in-LDS deinterleave
    dwt_quad_eo<<<2048, BT, 0, stream>>>(wsB, out);
}